// Round 6
// baseline (232.775 us; speedup 1.0000x reference)
//
#include <hip/hip_runtime.h>
#include <hip/hip_bf16.h>
#include <math.h>

#define B_N   2000
#define T_N   32
#define CIN_N 32
#define COUT_N 128
#define E_N   32000
#define NEG_S 0.01f
#define EPS_S 1e-5f
#define NNODE (B_N * T_N)   // 64000
#define EPAD_N 38016        // padded CSR capacity (multiple-of-4 per node)

typedef __attribute__((ext_vector_type(8))) __bf16 bf16x8;
typedef __attribute__((ext_vector_type(4))) float f32x4;

__device__ __forceinline__ unsigned short f2bf(float f) {
  unsigned u = __builtin_bit_cast(unsigned, f);
  u += 0x7FFFu + ((u >> 16) & 1u);   // RNE (finite values)
  return (unsigned short)(u >> 16);
}
__device__ __forceinline__ float bf2f(unsigned short h) {
  unsigned u = ((unsigned)h) << 16;
  return __builtin_bit_cast(float, u);
}

// ---------------- Kernel 0a: conv weights fp32 -> bf16 (layout [co][96] is already B-operand) ----
__global__ void k_cwcast(const float* __restrict__ cw, unsigned short* __restrict__ wTc)
{
  int idx = blockIdx.x * 256 + threadIdx.x;   // 12288
  if (idx >= 128 * 96) return;
  wTc[idx] = f2bf(cw[idx]);
}

// ---------------- Kernel 0b: tag weights [3][128][128] -> bf16 [col j][concat K] ----------------
__global__ void k_twt(const float* __restrict__ tw, unsigned short* __restrict__ wTt)
{
  int idx = blockIdx.x * 256 + threadIdx.x;   // 49152
  if (idx >= 128 * 384) return;
  int j = idx / 384, kk = idx - j * 384;
  int k = kk >> 7, i = kk & 127;
  wTt[idx] = f2bf(tw[k * 16384 + i * 128 + j]);
}

// ---------------- Kernel 1a: im2col A[t*B+b][k] bf16, k = ci*3+kk, causal pad ----------------
__global__ __launch_bounds__(256) void k_im2col(const float* __restrict__ x,
                                                unsigned short* __restrict__ A)
{
  __shared__ float sx[32 * 34];   // x[b] padded: sx[ci*34 + t+2] = x[b,ci,t]
  const int b = blockIdx.x;
  const int tid = threadIdx.x;
  for (int idx = tid; idx < 1088; idx += 256) {
    int ci = idx / 34, tt = idx - ci * 34;
    sx[idx] = (tt >= 2) ? x[b * 1024 + ci * 32 + (tt - 2)] : 0.f;
  }
  __syncthreads();
  #pragma unroll
  for (int i = 0; i < 12; ++i) {
    int idx = i * 256 + tid;                 // 3072 = 32*96
    int t = idx / 96, k = idx - t * 96;
    int ci = k / 3, kk = k - ci * 3;
    A[(size_t)(t * B_N + b) * 96 + k] = f2bf(sx[ci * 34 + t + kk]);
  }
}

// ---------------- Kernel 1b: MFMA conv GEMM M=64000 K=96 N=128 + bias + LeakyReLU ----------------
// Col-split: each wave does 16 rows x 64 cols (half = gid&1). 8000 waves.
__global__ __launch_bounds__(256) void k_convmm(
    const unsigned short* __restrict__ A, const unsigned short* __restrict__ wTc,
    const float* __restrict__ cb, unsigned short* __restrict__ xcat)
{
  const int gid = (blockIdx.x * 256 + threadIdx.x) >> 6;
  const int wid = gid >> 1, half = gid & 1;
  const int lane = threadIdx.x & 63;
  const int m0 = wid * 16;
  const int r = lane & 15, q = lane >> 4;

  const bf16x8* arow = (const bf16x8*)(A + (size_t)(m0 + r) * 96 + q * 8);
  const bf16x8* brow = (const bf16x8*)(wTc + (size_t)r * 96 + q * 8) + half * 4 * 192;

  f32x4 acc[4] = {};
  #pragma unroll
  for (int ks = 0; ks < 3; ++ks) {
    bf16x8 a = arow[ks * 4];
    #pragma unroll
    for (int nf = 0; nf < 4; ++nf) {
      bf16x8 bv = brow[nf * 192 + ks * 4];   // col block (half*4+nf)*16
      acc[nf] = __builtin_amdgcn_mfma_f32_16x16x32_bf16(a, bv, acc[nf], 0, 0, 0);
    }
  }

  #pragma unroll
  for (int nf = 0; nf < 4; ++nf) {
    const int col = (half * 4 + nf) * 16 + r;
    const float bias = cb[col];
    #pragma unroll
    for (int i = 0; i < 4; ++i) {
      const int row = m0 + q * 4 + i;
      float u = acc[nf][i] + bias;
      u = (u >= 0.f) ? u : NEG_S * u;
      xcat[(size_t)row * 384 + col] = f2bf(u);
    }
  }
}

// ---------------- Kernel 1c: per-sample LayerNorm in place over xcat cols 0..127 ----------------
__global__ __launch_bounds__(256) void k_ln(
    unsigned short* xcat, const float* __restrict__ gamma, const float* __restrict__ beta)
{
  __shared__ float red1[4], red2[4], sstat[2];
  const int b = blockIdx.x;
  const int tid = threadIdx.x;
  float vals[16];
  float s1 = 0.f, s2 = 0.f;
  #pragma unroll
  for (int i = 0; i < 16; ++i) {
    int idx = i * 256 + tid;
    int t = idx >> 7, c = idx & 127;
    float v = bf2f(xcat[(size_t)(t * B_N + b) * 384 + c]);
    vals[i] = v; s1 += v; s2 += v * v;
  }
  const int lane = tid & 63, wid = tid >> 6;
  #pragma unroll
  for (int d = 32; d > 0; d >>= 1) {
    s1 += __shfl_down(s1, d);
    s2 += __shfl_down(s2, d);
  }
  if (lane == 0) { red1[wid] = s1; red2[wid] = s2; }
  __syncthreads();
  if (tid == 0) {
    float a = red1[0] + red1[1] + red1[2] + red1[3];
    float c = red2[0] + red2[1] + red2[2] + red2[3];
    float mu = a / 4096.f;
    float var = c / 4096.f - mu * mu;
    sstat[0] = mu;
    sstat[1] = rsqrtf(var + EPS_S);
  }
  __syncthreads();
  const float mu = sstat[0], rs = sstat[1];
  #pragma unroll
  for (int i = 0; i < 16; ++i) {
    int idx = i * 256 + tid;
    int t = idx >> 7, c = idx & 127;
    float g  = gamma[c * 32 + t];
    float be = beta[c * 32 + t];
    xcat[(size_t)(t * B_N + b) * 384 + c] = f2bf((vals[i] - mu) * rs * g + be);
  }
}

// ---------------- Kernel 2: in-degree (weighted) + in-edge counts ----------------
__global__ void k_deg(const int* __restrict__ ei, const float* __restrict__ ew,
                      float* __restrict__ deg, int* __restrict__ cnt)
{
  int e = blockIdx.x * 256 + threadIdx.x;
  if (e >= E_N) return;
  int d = ei[E_N + e];
  atomicAdd(&deg[d], ew[e]);
  atomicAdd(&cnt[d], 1);
}

// ---------------- Kernel 3: single-block exclusive scan over 2000 PADDED counts ----------------
__global__ __launch_bounds__(256) void k_scan(const int* __restrict__ cnt, int* __restrict__ offs)
{
  __shared__ int wsum[4];
  int tid = threadIdx.x;
  int vals[8];
  int run = 0;
  #pragma unroll
  for (int i = 0; i < 8; ++i) {
    int idx = tid * 8 + i;
    vals[i] = run;
    int v = (idx < B_N) ? cnt[idx] : 0;
    v = (v + 3) & ~3;                       // pad to multiple of 4
    run += v;
  }
  int lane = tid & 63, wid = tid >> 6;
  int xs = run;
  #pragma unroll
  for (int d = 1; d < 64; d <<= 1) {
    int y = __shfl_up(xs, d);
    if (lane >= d) xs += y;
  }
  if (lane == 63) wsum[wid] = xs;
  __syncthreads();
  int pre = 0;
  for (int w = 0; w < wid; ++w) pre += wsum[w];
  int excl = pre + xs - run;
  #pragma unroll
  for (int i = 0; i < 8; ++i) {
    int idx = tid * 8 + i;
    if (idx <= B_N) offs[idx] = excl + vals[i];
  }
}

// ---------------- Kernel 4: CSR scatter + edge norm (pad slots stay {src=0, norm=0}) ----------------
__global__ void k_scatter(const int* __restrict__ ei, const float* __restrict__ ew,
                          const float* __restrict__ deg, const int* __restrict__ offs,
                          int* __restrict__ cursor, int* __restrict__ csr_src,
                          float* __restrict__ csr_norm)
{
  int e = blockIdx.x * 256 + threadIdx.x;
  if (e >= E_N) return;
  int s = ei[e], d = ei[E_N + e];
  float ds_ = deg[s], dd = deg[d];
  float dis_s = (ds_ > 0.f) ? rsqrtf(fmaxf(ds_, 1e-12f)) : 0.f;
  float dis_d = (dd  > 0.f) ? rsqrtf(fmaxf(dd,  1e-12f)) : 0.f;
  float nrm = dis_s * ew[e] * dis_d;
  int pos = offs[d] + atomicAdd(&cursor[d], 1);
  csr_src[pos] = s;
  csr_norm[pos] = nrm;
}

// ---------------- Kernel 5: one-hop propagation, 4-wide edge unroll ----------------
__global__ __launch_bounds__(256) void k_prop(
    unsigned short* xcat, int cin, int cout_,
    const int* __restrict__ offs, const int* __restrict__ csr_src,
    const float* __restrict__ csr_norm)
{
  int gw = (blockIdx.x * 256 + threadIdx.x) >> 6;
  int lane = threadIdx.x & 63;
  if (gw >= NNODE) return;
  int t = gw / B_N;
  int b = gw - t * B_N;
  int beg = offs[b], end = offs[b + 1];           // both multiples of 4
  const unsigned short* base = xcat + (size_t)t * B_N * 384 + cin + lane * 2;
  float ax0 = 0.f, ay0 = 0.f, ax1 = 0.f, ay1 = 0.f;
  float ax2 = 0.f, ay2 = 0.f, ax3 = 0.f, ay3 = 0.f;
  for (int i = beg; i < end; i += 4) {
    int4   s4 = *(const int4*)&csr_src[i];
    float4 n4 = *(const float4*)&csr_norm[i];
    ushort2 v0 = *(const ushort2*)(base + (size_t)s4.x * 384);
    ushort2 v1 = *(const ushort2*)(base + (size_t)s4.y * 384);
    ushort2 v2 = *(const ushort2*)(base + (size_t)s4.z * 384);
    ushort2 v3 = *(const ushort2*)(base + (size_t)s4.w * 384);
    ax0 += n4.x * bf2f(v0.x); ay0 += n4.x * bf2f(v0.y);
    ax1 += n4.y * bf2f(v1.x); ay1 += n4.y * bf2f(v1.y);
    ax2 += n4.z * bf2f(v2.x); ay2 += n4.z * bf2f(v2.y);
    ax3 += n4.w * bf2f(v3.x); ay3 += n4.w * bf2f(v3.y);
  }
  float ax = (ax0 + ax1) + (ax2 + ax3);
  float ay = (ay0 + ay1) + (ay2 + ay3);
  ushort2 o; o.x = f2bf(ax); o.y = f2bf(ay);
  *(ushort2*)&xcat[(size_t)gw * 384 + cout_ + lane * 2] = o;
}

// ---------------- Kernel 6: MFMA triple-GEMM (K=384) + bias + LeakyReLU + residual ----------------
// Col-split: each wave does 16 rows x 64 cols (half = gid&1). 8000 waves.
__global__ __launch_bounds__(256) void k_gemm(
    const unsigned short* __restrict__ xcat, const unsigned short* __restrict__ wTt,
    const float* __restrict__ tb, float* __restrict__ outn)
{
  const int gid = (blockIdx.x * 256 + threadIdx.x) >> 6;
  const int wid = gid >> 1, half = gid & 1;
  const int lane = threadIdx.x & 63;
  const int m0 = wid * 16;
  const int r = lane & 15, q = lane >> 4;

  const bf16x8* arow = (const bf16x8*)(xcat + (size_t)(m0 + r) * 384 + q * 8);
  const bf16x8* brow = (const bf16x8*)(wTt + (size_t)r * 384 + q * 8) + half * 4 * 768;

  f32x4 acc[4] = {};
  #pragma unroll
  for (int ks = 0; ks < 12; ++ks) {
    bf16x8 a = arow[ks * 4];
    #pragma unroll
    for (int nf = 0; nf < 4; ++nf) {
      bf16x8 bf = brow[nf * 768 + ks * 4];
      acc[nf] = __builtin_amdgcn_mfma_f32_16x16x32_bf16(a, bf, acc[nf], 0, 0, 0);
    }
  }

  #pragma unroll
  for (int nf = 0; nf < 4; ++nf) {
    const int col = (half * 4 + nf) * 16 + r;
    const float bias = tb[col];
    #pragma unroll
    for (int i = 0; i < 4; ++i) {
      const int row = m0 + q * 4 + i;
      float u = acc[nf][i] + bias;
      u = (u >= 0.f) ? u : NEG_S * u;
      float xv = bf2f(xcat[(size_t)row * 384 + col]);
      outn[(size_t)row * 128 + col] = xv + u;
    }
  }
}

// ---------------- Kernel 7: transpose [t*B+b][c] -> [b][c][t] ----------------
__global__ __launch_bounds__(256) void k_out(const float* __restrict__ hfin, float* __restrict__ out)
{
  __shared__ float lds[32 * 129];
  const int b = blockIdx.x, tid = threadIdx.x;
  #pragma unroll
  for (int i = 0; i < 16; ++i) {
    int idx = i * 256 + tid;
    int t = idx >> 7, c = idx & 127;
    lds[t * 129 + c] = hfin[(size_t)(t * B_N + b) * 128 + c];
  }
  __syncthreads();
  #pragma unroll
  for (int i = 0; i < 16; ++i) {
    int idx = i * 256 + tid;
    int c = idx >> 5, t = idx & 31;
    out[(size_t)b * 4096 + c * 32 + t] = lds[t * 129 + c];
  }
}

extern "C" void kernel_launch(void* const* d_in, const int* in_sizes, int n_in,
                              void* d_out, int out_size, void* d_ws, size_t ws_size,
                              hipStream_t stream)
{
  const float* x     = (const float*)d_in[0];
  const int*   ei    = (const int*)d_in[1];
  const float* ew    = (const float*)d_in[2];
  const float* cw    = (const float*)d_in[3];
  const float* cb    = (const float*)d_in[4];
  const float* gamma = (const float*)d_in[5];
  const float* beta  = (const float*)d_in[6];
  const float* tw    = (const float*)d_in[7];
  const float* tb    = (const float*)d_in[8];
  float* out = (float*)d_out;

  // workspace layout
  float* outn = (float*)d_ws;                                             // 64000*128 fp32
  unsigned short* A = (unsigned short*)outn;                              // 64000*96 bf16, aliased:
                                                                          // dead before k_gemm writes outn
  unsigned short* xcat = (unsigned short*)(outn + (size_t)NNODE * 128);   // 64000*384 bf16
  float* deg = (float*)(xcat + (size_t)NNODE * 384);                      // 2000
  int*   cnt    = (int*)(deg + B_N);                                      // 2000
  int*   cursor = cnt + B_N;                                              // 2000
  int*   offs   = cursor + B_N;                                           // 2001
  int*   csr_src = offs + (B_N + 1);                                      // EPAD_N
  float* csr_norm = (float*)(csr_src + EPAD_N);                           // EPAD_N
  unsigned short* wTc = (unsigned short*)(csr_norm + EPAD_N);             // 128*96 bf16
  unsigned short* wTt = wTc + 128 * 96;                                   // 128*384 bf16

  hipMemsetAsync(deg, 0, (size_t)3 * B_N * 4, stream);                    // deg+cnt+cursor
  hipMemsetAsync(csr_src, 0, (size_t)EPAD_N * 8, stream);                 // csr_src+csr_norm

  k_cwcast<<<(128 * 96 + 255) / 256, 256, 0, stream>>>(cw, wTc);
  k_twt<<<(128 * 384 + 255) / 256, 256, 0, stream>>>(tw, wTt);
  k_im2col<<<B_N, 256, 0, stream>>>(x, A);
  k_convmm<<<NNODE / 16 / 2, 256, 0, stream>>>(A, wTc, cb, xcat);   // 8000 waves / 4 per block
  k_ln<<<B_N, 256, 0, stream>>>(xcat, gamma, beta);
  k_deg<<<(E_N + 255) / 256, 256, 0, stream>>>(ei, ew, deg, cnt);
  k_scan<<<1, 256, 0, stream>>>(cnt, offs);
  k_scatter<<<(E_N + 255) / 256, 256, 0, stream>>>(ei, ew, deg, offs, cursor, csr_src, csr_norm);
  k_prop<<<NNODE / 4, 256, 0, stream>>>(xcat, 0, 128, offs, csr_src, csr_norm);
  k_prop<<<NNODE / 4, 256, 0, stream>>>(xcat, 128, 256, offs, csr_src, csr_norm);
  k_gemm<<<NNODE / 16 / 2, 256, 0, stream>>>(xcat, wTt, tb, outn);  // 8000 waves
  k_out<<<B_N, 256, 0, stream>>>(outn, out);
}

// Round 7
// 191.281 us; speedup vs baseline: 1.2169x; 1.2169x over previous
//
#include <hip/hip_runtime.h>
#include <hip/hip_bf16.h>
#include <math.h>

#define B_N   2000
#define T_N   32
#define CIN_N 32
#define COUT_N 128
#define E_N   32000
#define NEG_S 0.01f
#define EPS_S 1e-5f
#define NNODE (B_N * T_N)   // 64000
#define EPAD_N 38016        // padded CSR capacity (multiple-of-4 per node)

typedef __attribute__((ext_vector_type(8))) __bf16 bf16x8;
typedef __attribute__((ext_vector_type(4))) float f32x4;

__device__ __forceinline__ unsigned short f2bf(float f) {
  unsigned u = __builtin_bit_cast(unsigned, f);
  u += 0x7FFFu + ((u >> 16) & 1u);   // RNE (finite values)
  return (unsigned short)(u >> 16);
}
__device__ __forceinline__ float bf2f(unsigned short h) {
  unsigned u = ((unsigned)h) << 16;
  return __builtin_bit_cast(float, u);
}

// ---------------- Kernel 0a: conv weights -> bf16 in MFMA-fragment order ----------------
// wBc[((nf2*3+ks)*64+lane)*8+e] = cw[col*96 + k], col=nf2*16+(lane&15), k=ks*32+(lane>>4)*8+e
__global__ void k_cwcast(const float* __restrict__ cw, unsigned short* __restrict__ wBc)
{
  int idx = blockIdx.x * 256 + threadIdx.x;   // 12288 = 8*3*64*8
  if (idx >= 12288) return;
  int e = idx & 7, lane = (idx >> 3) & 63, rest = idx >> 9;
  int ks = rest % 3, nf2 = rest / 3;
  int col = nf2 * 16 + (lane & 15);
  int k = ks * 32 + ((lane >> 4) << 3) + e;
  wBc[idx] = f2bf(cw[col * 96 + k]);
}

// ---------------- Kernel 0b: tag weights -> bf16 in MFMA-fragment order ----------------
// wB[((nf2*12+ks)*64+lane)*8+e] = tag_w[hop][i][col], col=nf2*16+(lane&15),
//   k=ks*32+(lane>>4)*8+e, hop=k>>7, i=k&127
__global__ void k_twt(const float* __restrict__ tw, unsigned short* __restrict__ wB)
{
  int idx = blockIdx.x * 256 + threadIdx.x;   // 49152 = 8*12*64*8
  if (idx >= 49152) return;
  int e = idx & 7, lane = (idx >> 3) & 63, rest = idx >> 9;
  int ks = rest % 12, nf2 = rest / 12;
  int col = nf2 * 16 + (lane & 15);
  int k = ks * 32 + ((lane >> 4) << 3) + e;
  int hop = k >> 7, i = k & 127;
  wB[idx] = f2bf(tw[hop * 16384 + i * 128 + col]);
}

// ---------------- Kernel 1a: im2col A[t*B+b][k] bf16, k = ci*3+kk, causal pad ----------------
__global__ __launch_bounds__(256) void k_im2col(const float* __restrict__ x,
                                                unsigned short* __restrict__ A)
{
  __shared__ float sx[32 * 34];   // x[b] padded: sx[ci*34 + t+2] = x[b,ci,t]
  const int b = blockIdx.x;
  const int tid = threadIdx.x;
  for (int idx = tid; idx < 1088; idx += 256) {
    int ci = idx / 34, tt = idx - ci * 34;
    sx[idx] = (tt >= 2) ? x[b * 1024 + ci * 32 + (tt - 2)] : 0.f;
  }
  __syncthreads();
  #pragma unroll
  for (int i = 0; i < 12; ++i) {
    int idx = i * 256 + tid;                 // 3072 = 32*96
    int t = idx / 96, k = idx - t * 96;
    int ci = k / 3, kk = k - ci * 3;
    A[(size_t)(t * B_N + b) * 96 + k] = f2bf(sx[ci * 34 + t + kk]);
  }
}

// ---------------- Kernel 1b: MFMA conv GEMM, B staged in LDS fragment-order ----------------
// Block = 8 waves x 16 rows = 128 rows, all 128 cols. Grid 500.
__global__ __launch_bounds__(512, 4) void k_convmm(
    const unsigned short* __restrict__ A, const unsigned short* __restrict__ wBc,
    const float* __restrict__ cb, unsigned short* __restrict__ xcat)
{
  __shared__ unsigned short sB[12288];   // 24KB
  const int tid = threadIdx.x;
  const int w = tid >> 6, lane = tid & 63;
  const int m0 = blockIdx.x * 128 + w * 16;
  const int r = lane & 15, q = lane >> 4;

  // A fragments up-front (3 independent loads)
  const bf16x8* arow = (const bf16x8*)(A + (size_t)(m0 + r) * 96 + q * 8);
  bf16x8 a0 = arow[0], a1 = arow[4], a2 = arow[8];

  // linear stage of fragment-ordered B
  #pragma unroll
  for (int i = 0; i < 3; ++i) {
    int id = i * 512 + tid;                // 1536 float4
    ((float4*)sB)[id] = ((const float4*)wBc)[id];
  }
  __syncthreads();

  f32x4 acc[8] = {};
  #pragma unroll
  for (int ks = 0; ks < 3; ++ks) {
    bf16x8 a = (ks == 0) ? a0 : (ks == 1) ? a1 : a2;
    #pragma unroll
    for (int nf = 0; nf < 8; ++nf) {
      bf16x8 bv = *(const bf16x8*)&sB[((nf * 3 + ks) * 64 + lane) * 8];
      acc[nf] = __builtin_amdgcn_mfma_f32_16x16x32_bf16(a, bv, acc[nf], 0, 0, 0);
    }
  }

  #pragma unroll
  for (int nf = 0; nf < 8; ++nf) {
    const int col = nf * 16 + r;
    const float bias = cb[col];
    #pragma unroll
    for (int i = 0; i < 4; ++i) {
      const int row = m0 + q * 4 + i;
      float u = acc[nf][i] + bias;
      u = (u >= 0.f) ? u : NEG_S * u;
      xcat[(size_t)row * 384 + col] = f2bf(u);
    }
  }
}

// ---------------- Kernel 1c: per-sample LayerNorm in place over xcat cols 0..127 ----------------
__global__ __launch_bounds__(256) void k_ln(
    unsigned short* xcat, const float* __restrict__ gamma, const float* __restrict__ beta)
{
  __shared__ float red1[4], red2[4], sstat[2];
  const int b = blockIdx.x;
  const int tid = threadIdx.x;
  float vals[16];
  float s1 = 0.f, s2 = 0.f;
  #pragma unroll
  for (int i = 0; i < 16; ++i) {
    int idx = i * 256 + tid;
    int t = idx >> 7, c = idx & 127;
    float v = bf2f(xcat[(size_t)(t * B_N + b) * 384 + c]);
    vals[i] = v; s1 += v; s2 += v * v;
  }
  const int lane = tid & 63, wid = tid >> 6;
  #pragma unroll
  for (int d = 32; d > 0; d >>= 1) {
    s1 += __shfl_down(s1, d);
    s2 += __shfl_down(s2, d);
  }
  if (lane == 0) { red1[wid] = s1; red2[wid] = s2; }
  __syncthreads();
  if (tid == 0) {
    float a = red1[0] + red1[1] + red1[2] + red1[3];
    float c = red2[0] + red2[1] + red2[2] + red2[3];
    float mu = a / 4096.f;
    float var = c / 4096.f - mu * mu;
    sstat[0] = mu;
    sstat[1] = rsqrtf(var + EPS_S);
  }
  __syncthreads();
  const float mu = sstat[0], rs = sstat[1];
  #pragma unroll
  for (int i = 0; i < 16; ++i) {
    int idx = i * 256 + tid;
    int t = idx >> 7, c = idx & 127;
    float g  = gamma[c * 32 + t];
    float be = beta[c * 32 + t];
    xcat[(size_t)(t * B_N + b) * 384 + c] = f2bf((vals[i] - mu) * rs * g + be);
  }
}

// ---------------- Kernel 2: in-degree (weighted) + in-edge counts ----------------
__global__ void k_deg(const int* __restrict__ ei, const float* __restrict__ ew,
                      float* __restrict__ deg, int* __restrict__ cnt)
{
  int e = blockIdx.x * 256 + threadIdx.x;
  if (e >= E_N) return;
  int d = ei[E_N + e];
  atomicAdd(&deg[d], ew[e]);
  atomicAdd(&cnt[d], 1);
}

// ---------------- Kernel 3: single-block exclusive scan over 2000 PADDED counts ----------------
__global__ __launch_bounds__(256) void k_scan(const int* __restrict__ cnt, int* __restrict__ offs)
{
  __shared__ int wsum[4];
  int tid = threadIdx.x;
  int vals[8];
  int run = 0;
  #pragma unroll
  for (int i = 0; i < 8; ++i) {
    int idx = tid * 8 + i;
    vals[i] = run;
    int v = (idx < B_N) ? cnt[idx] : 0;
    v = (v + 3) & ~3;                       // pad to multiple of 4
    run += v;
  }
  int lane = tid & 63, wid = tid >> 6;
  int xs = run;
  #pragma unroll
  for (int d = 1; d < 64; d <<= 1) {
    int y = __shfl_up(xs, d);
    if (lane >= d) xs += y;
  }
  if (lane == 63) wsum[wid] = xs;
  __syncthreads();
  int pre = 0;
  for (int w = 0; w < wid; ++w) pre += wsum[w];
  int excl = pre + xs - run;
  #pragma unroll
  for (int i = 0; i < 8; ++i) {
    int idx = tid * 8 + i;
    if (idx <= B_N) offs[idx] = excl + vals[i];
  }
}

// ---------------- Kernel 4: CSR scatter + edge norm (pad slots stay {src=0, norm=0}) ----------------
__global__ void k_scatter(const int* __restrict__ ei, const float* __restrict__ ew,
                          const float* __restrict__ deg, const int* __restrict__ offs,
                          int* __restrict__ cursor, int* __restrict__ csr_src,
                          float* __restrict__ csr_norm)
{
  int e = blockIdx.x * 256 + threadIdx.x;
  if (e >= E_N) return;
  int s = ei[e], d = ei[E_N + e];
  float ds_ = deg[s], dd = deg[d];
  float dis_s = (ds_ > 0.f) ? rsqrtf(fmaxf(ds_, 1e-12f)) : 0.f;
  float dis_d = (dd  > 0.f) ? rsqrtf(fmaxf(dd,  1e-12f)) : 0.f;
  float nrm = dis_s * ew[e] * dis_d;
  int pos = offs[d] + atomicAdd(&cursor[d], 1);
  csr_src[pos] = s;
  csr_norm[pos] = nrm;
}

// ---------------- Kernel 5: one-hop propagation, 4-wide edge unroll ----------------
__global__ __launch_bounds__(256) void k_prop(
    unsigned short* xcat, int cin, int cout_,
    const int* __restrict__ offs, const int* __restrict__ csr_src,
    const float* __restrict__ csr_norm)
{
  int gw = (blockIdx.x * 256 + threadIdx.x) >> 6;
  int lane = threadIdx.x & 63;
  if (gw >= NNODE) return;
  int t = gw / B_N;
  int b = gw - t * B_N;
  int beg = offs[b], end = offs[b + 1];           // both multiples of 4
  const unsigned short* base = xcat + (size_t)t * B_N * 384 + cin + lane * 2;
  float ax0 = 0.f, ay0 = 0.f, ax1 = 0.f, ay1 = 0.f;
  float ax2 = 0.f, ay2 = 0.f, ax3 = 0.f, ay3 = 0.f;
  for (int i = beg; i < end; i += 4) {
    int4   s4 = *(const int4*)&csr_src[i];
    float4 n4 = *(const float4*)&csr_norm[i];
    ushort2 v0 = *(const ushort2*)(base + (size_t)s4.x * 384);
    ushort2 v1 = *(const ushort2*)(base + (size_t)s4.y * 384);
    ushort2 v2 = *(const ushort2*)(base + (size_t)s4.z * 384);
    ushort2 v3 = *(const ushort2*)(base + (size_t)s4.w * 384);
    ax0 += n4.x * bf2f(v0.x); ay0 += n4.x * bf2f(v0.y);
    ax1 += n4.y * bf2f(v1.x); ay1 += n4.y * bf2f(v1.y);
    ax2 += n4.z * bf2f(v2.x); ay2 += n4.z * bf2f(v2.y);
    ax3 += n4.w * bf2f(v3.x); ay3 += n4.w * bf2f(v3.y);
  }
  float ax = (ax0 + ax1) + (ax2 + ax3);
  float ay = (ay0 + ay1) + (ay2 + ay3);
  ushort2 o; o.x = f2bf(ax); o.y = f2bf(ay);
  *(ushort2*)&xcat[(size_t)gw * 384 + cout_ + lane * 2] = o;
}

// ---------------- Kernel 6: MFMA triple-GEMM (K=384), B half in LDS fragment-order ----------------
// Block = 8 waves x 16 rows = 128 rows x 64 cols (half). Grid 1000 (500 rowblks x 2 halves).
__global__ __launch_bounds__(512, 4) void k_gemm(
    const unsigned short* __restrict__ xcat, const unsigned short* __restrict__ wB,
    const float* __restrict__ tb, float* __restrict__ outn)
{
  __shared__ unsigned short sB[24576];   // 48KB = 64 cols x 384 K, fragment-ordered
  const int bid = blockIdx.x;
  const int half = bid / 500, rowblk = bid % 500;
  const int tid = threadIdx.x;
  const int w = tid >> 6, lane = tid & 63;
  const int m0 = rowblk * 128 + w * 16;
  const int r = lane & 15, q = lane >> 4;

  // all 12 A fragments up-front (independent loads, one round trip)
  const bf16x8* arow = (const bf16x8*)(xcat + (size_t)(m0 + r) * 384 + q * 8);
  bf16x8 a[12];
  #pragma unroll
  for (int ks = 0; ks < 12; ++ks) a[ks] = arow[ks * 4];

  // linear stage of this half's fragment-ordered B (24576 elems = 3072 float4)
  const float4* gB = (const float4*)(wB + (size_t)half * 24576);
  #pragma unroll
  for (int i = 0; i < 6; ++i) {
    int id = i * 512 + tid;
    ((float4*)sB)[id] = gB[id];
  }
  __syncthreads();

  f32x4 acc[4] = {};
  #pragma unroll
  for (int ks = 0; ks < 12; ++ks) {
    #pragma unroll
    for (int nf = 0; nf < 4; ++nf) {
      bf16x8 bv = *(const bf16x8*)&sB[((nf * 12 + ks) * 64 + lane) * 8];
      acc[nf] = __builtin_amdgcn_mfma_f32_16x16x32_bf16(a[ks], bv, acc[nf], 0, 0, 0);
    }
  }

  #pragma unroll
  for (int nf = 0; nf < 4; ++nf) {
    const int col = (half * 4 + nf) * 16 + r;
    const float bias = tb[col];
    #pragma unroll
    for (int i = 0; i < 4; ++i) {
      const int row = m0 + q * 4 + i;
      float u = acc[nf][i] + bias;
      u = (u >= 0.f) ? u : NEG_S * u;
      float xv = bf2f(xcat[(size_t)row * 384 + col]);
      outn[(size_t)row * 128 + col] = xv + u;
    }
  }
}

// ---------------- Kernel 7: transpose [t*B+b][c] -> [b][c][t] ----------------
__global__ __launch_bounds__(256) void k_out(const float* __restrict__ hfin, float* __restrict__ out)
{
  __shared__ float lds[32 * 129];
  const int b = blockIdx.x, tid = threadIdx.x;
  #pragma unroll
  for (int i = 0; i < 16; ++i) {
    int idx = i * 256 + tid;
    int t = idx >> 7, c = idx & 127;
    lds[t * 129 + c] = hfin[(size_t)(t * B_N + b) * 128 + c];
  }
  __syncthreads();
  #pragma unroll
  for (int i = 0; i < 16; ++i) {
    int idx = i * 256 + tid;
    int c = idx >> 5, t = idx & 31;
    out[(size_t)b * 4096 + c * 32 + t] = lds[t * 129 + c];
  }
}

extern "C" void kernel_launch(void* const* d_in, const int* in_sizes, int n_in,
                              void* d_out, int out_size, void* d_ws, size_t ws_size,
                              hipStream_t stream)
{
  const float* x     = (const float*)d_in[0];
  const int*   ei    = (const int*)d_in[1];
  const float* ew    = (const float*)d_in[2];
  const float* cw    = (const float*)d_in[3];
  const float* cb    = (const float*)d_in[4];
  const float* gamma = (const float*)d_in[5];
  const float* beta  = (const float*)d_in[6];
  const float* tw    = (const float*)d_in[7];
  const float* tb    = (const float*)d_in[8];
  float* out = (float*)d_out;

  // workspace layout
  float* outn = (float*)d_ws;                                             // 64000*128 fp32
  unsigned short* A = (unsigned short*)outn;                              // 64000*96 bf16 aliased
                                                                          // (dead before k_gemm writes outn)
  unsigned short* xcat = (unsigned short*)(outn + (size_t)NNODE * 128);   // 64000*384 bf16
  float* deg = (float*)(xcat + (size_t)NNODE * 384);                      // 2000
  int*   cnt    = (int*)(deg + B_N);                                      // 2000
  int*   cursor = cnt + B_N;                                              // 2000
  int*   offs   = cursor + B_N;                                           // 2001 (+3 pad for 16B align)
  int*   csr_src = offs + (B_N + 4);                                      // EPAD_N, 16B-aligned
  float* csr_norm = (float*)(csr_src + EPAD_N);                           // EPAD_N
  unsigned short* wBc = (unsigned short*)(csr_norm + EPAD_N);             // 12288 bf16 frag-order
  unsigned short* wB  = wBc + 12288;                                      // 49152 bf16 frag-order

  hipMemsetAsync(deg, 0, (size_t)3 * B_N * 4, stream);                    // deg+cnt+cursor
  hipMemsetAsync(csr_src, 0, (size_t)EPAD_N * 8, stream);                 // csr_src+csr_norm

  k_cwcast<<<48, 256, 0, stream>>>(cw, wBc);
  k_twt<<<192, 256, 0, stream>>>(tw, wB);
  k_im2col<<<B_N, 256, 0, stream>>>(x, A);
  k_convmm<<<500, 512, 0, stream>>>(A, wBc, cb, xcat);
  k_ln<<<B_N, 256, 0, stream>>>(xcat, gamma, beta);
  k_deg<<<(E_N + 255) / 256, 256, 0, stream>>>(ei, ew, deg, cnt);
  k_scan<<<1, 256, 0, stream>>>(cnt, offs);
  k_scatter<<<(E_N + 255) / 256, 256, 0, stream>>>(ei, ew, deg, offs, cursor, csr_src, csr_norm);
  k_prop<<<NNODE / 4, 256, 0, stream>>>(xcat, 0, 128, offs, csr_src, csr_norm);
  k_prop<<<NNODE / 4, 256, 0, stream>>>(xcat, 128, 256, offs, csr_src, csr_norm);
  k_gemm<<<1000, 512, 0, stream>>>(xcat, wB, tb, outn);
  k_out<<<B_N, 256, 0, stream>>>(outn, out);
}

// Round 8
// 189.460 us; speedup vs baseline: 1.2286x; 1.0096x over previous
//
#include <hip/hip_runtime.h>
#include <hip/hip_bf16.h>
#include <math.h>

#define B_N   2000
#define T_N   32
#define CIN_N 32
#define COUT_N 128
#define E_N   32000
#define NEG_S 0.01f
#define EPS_S 1e-5f
#define NNODE (B_N * T_N)   // 64000
#define EPAD_N 38016        // padded CSR capacity (multiple-of-4 per node)
// contiguous meta region: deg(2000)+cnt(2000)+cursor(2000)+offs(2004)+csr_src(38016)+csr_norm(38016)
#define META_I4 21009       // total ints 84036 = 21009 int4

typedef __attribute__((ext_vector_type(8))) __bf16 bf16x8;
typedef __attribute__((ext_vector_type(4))) float f32x4;

__device__ __forceinline__ unsigned short f2bf(float f) {
  unsigned u = __builtin_bit_cast(unsigned, f);
  u += 0x7FFFu + ((u >> 16) & 1u);   // RNE (finite values)
  return (unsigned short)(u >> 16);
}
__device__ __forceinline__ float bf2f(unsigned short h) {
  unsigned u = ((unsigned)h) << 16;
  return __builtin_bit_cast(float, u);
}

// ---------------- Kernel Z: zero the whole meta region (replaces slow rocclr fills) ----------------
__global__ __launch_bounds__(256) void k_zero(int4* __restrict__ meta)
{
  const int4 z = {0, 0, 0, 0};
  for (int i = blockIdx.x * 256 + threadIdx.x; i < META_I4; i += gridDim.x * 256)
    meta[i] = z;
}

// ---------------- Kernel 0a: conv weights -> bf16 in MFMA-fragment order ----------------
// wBc[((nf2*3+ks)*64+lane)*8+e] = cw[col*96 + k], col=nf2*16+(lane&15), k=ks*32+(lane>>4)*8+e
__global__ void k_cwcast(const float* __restrict__ cw, unsigned short* __restrict__ wBc)
{
  int idx = blockIdx.x * 256 + threadIdx.x;   // 12288 = 8*3*64*8
  if (idx >= 12288) return;
  int e = idx & 7, lane = (idx >> 3) & 63, rest = idx >> 9;
  int ks = rest % 3, nf2 = rest / 3;
  int col = nf2 * 16 + (lane & 15);
  int k = ks * 32 + ((lane >> 4) << 3) + e;
  wBc[idx] = f2bf(cw[col * 96 + k]);
}

// ---------------- Kernel 0b: tag weights -> bf16 in MFMA-fragment order ----------------
// wB[((nf2*12+ks)*64+lane)*8+e] = tag_w[hop][i][col], col=nf2*16+(lane&15),
//   k=ks*32+(lane>>4)*8+e, hop=k>>7, i=k&127
__global__ void k_twt(const float* __restrict__ tw, unsigned short* __restrict__ wB)
{
  int idx = blockIdx.x * 256 + threadIdx.x;   // 49152 = 8*12*64*8
  if (idx >= 49152) return;
  int e = idx & 7, lane = (idx >> 3) & 63, rest = idx >> 9;
  int ks = rest % 12, nf2 = rest / 12;
  int col = nf2 * 16 + (lane & 15);
  int k = ks * 32 + ((lane >> 4) << 3) + e;
  int hop = k >> 7, i = k & 127;
  wB[idx] = f2bf(tw[hop * 16384 + i * 128 + col]);
}

// ---------------- Kernel 1a: im2col A[t*B+b][k] bf16, k = ci*3+kk, causal pad ----------------
__global__ __launch_bounds__(256) void k_im2col(const float* __restrict__ x,
                                                unsigned short* __restrict__ A)
{
  __shared__ float sx[32 * 34];   // x[b] padded: sx[ci*34 + t+2] = x[b,ci,t]
  const int b = blockIdx.x;
  const int tid = threadIdx.x;
  for (int idx = tid; idx < 1088; idx += 256) {
    int ci = idx / 34, tt = idx - ci * 34;
    sx[idx] = (tt >= 2) ? x[b * 1024 + ci * 32 + (tt - 2)] : 0.f;
  }
  __syncthreads();
  #pragma unroll
  for (int i = 0; i < 12; ++i) {
    int idx = i * 256 + tid;                 // 3072 = 32*96
    int t = idx / 96, k = idx - t * 96;
    int ci = k / 3, kk = k - ci * 3;
    A[(size_t)(t * B_N + b) * 96 + k] = f2bf(sx[ci * 34 + t + kk]);
  }
}

// ---------------- Kernel 1b: MFMA conv GEMM, B staged in LDS fragment-order ----------------
// Block = 8 waves x 16 rows = 128 rows, all 128 cols. Grid 500.
__global__ __launch_bounds__(512, 4) void k_convmm(
    const unsigned short* __restrict__ A, const unsigned short* __restrict__ wBc,
    const float* __restrict__ cb, unsigned short* __restrict__ xcat)
{
  __shared__ unsigned short sB[12288];   // 24KB
  const int tid = threadIdx.x;
  const int w = tid >> 6, lane = tid & 63;
  const int m0 = blockIdx.x * 128 + w * 16;
  const int r = lane & 15, q = lane >> 4;

  // A fragments up-front (3 independent loads)
  const bf16x8* arow = (const bf16x8*)(A + (size_t)(m0 + r) * 96 + q * 8);
  bf16x8 a0 = arow[0], a1 = arow[4], a2 = arow[8];

  // linear stage of fragment-ordered B
  #pragma unroll
  for (int i = 0; i < 3; ++i) {
    int id = i * 512 + tid;                // 1536 float4
    ((float4*)sB)[id] = ((const float4*)wBc)[id];
  }
  __syncthreads();

  f32x4 acc[8] = {};
  #pragma unroll
  for (int ks = 0; ks < 3; ++ks) {
    bf16x8 a = (ks == 0) ? a0 : (ks == 1) ? a1 : a2;
    #pragma unroll
    for (int nf = 0; nf < 8; ++nf) {
      bf16x8 bv = *(const bf16x8*)&sB[((nf * 3 + ks) * 64 + lane) * 8];
      acc[nf] = __builtin_amdgcn_mfma_f32_16x16x32_bf16(a, bv, acc[nf], 0, 0, 0);
    }
  }

  #pragma unroll
  for (int nf = 0; nf < 8; ++nf) {
    const int col = nf * 16 + r;
    const float bias = cb[col];
    #pragma unroll
    for (int i = 0; i < 4; ++i) {
      const int row = m0 + q * 4 + i;
      float u = acc[nf][i] + bias;
      u = (u >= 0.f) ? u : NEG_S * u;
      xcat[(size_t)row * 384 + col] = f2bf(u);
    }
  }
}

// ---------------- Kernel 1c: per-sample LayerNorm in place over xcat cols 0..127 ----------------
__global__ __launch_bounds__(256) void k_ln(
    unsigned short* xcat, const float* __restrict__ gamma, const float* __restrict__ beta)
{
  __shared__ float red1[4], red2[4], sstat[2];
  const int b = blockIdx.x;
  const int tid = threadIdx.x;
  float vals[16];
  float s1 = 0.f, s2 = 0.f;
  #pragma unroll
  for (int i = 0; i < 16; ++i) {
    int idx = i * 256 + tid;
    int t = idx >> 7, c = idx & 127;
    float v = bf2f(xcat[(size_t)(t * B_N + b) * 384 + c]);
    vals[i] = v; s1 += v; s2 += v * v;
  }
  const int lane = tid & 63, wid = tid >> 6;
  #pragma unroll
  for (int d = 32; d > 0; d >>= 1) {
    s1 += __shfl_down(s1, d);
    s2 += __shfl_down(s2, d);
  }
  if (lane == 0) { red1[wid] = s1; red2[wid] = s2; }
  __syncthreads();
  if (tid == 0) {
    float a = red1[0] + red1[1] + red1[2] + red1[3];
    float c = red2[0] + red2[1] + red2[2] + red2[3];
    float mu = a / 4096.f;
    float var = c / 4096.f - mu * mu;
    sstat[0] = mu;
    sstat[1] = rsqrtf(var + EPS_S);
  }
  __syncthreads();
  const float mu = sstat[0], rs = sstat[1];
  #pragma unroll
  for (int i = 0; i < 16; ++i) {
    int idx = i * 256 + tid;
    int t = idx >> 7, c = idx & 127;
    float g  = gamma[c * 32 + t];
    float be = beta[c * 32 + t];
    xcat[(size_t)(t * B_N + b) * 384 + c] = f2bf((vals[i] - mu) * rs * g + be);
  }
}

// ---------------- Kernel 2: in-degree (weighted) + in-edge counts ----------------
__global__ void k_deg(const int* __restrict__ ei, const float* __restrict__ ew,
                      float* __restrict__ deg, int* __restrict__ cnt)
{
  int e = blockIdx.x * 256 + threadIdx.x;
  if (e >= E_N) return;
  int d = ei[E_N + e];
  atomicAdd(&deg[d], ew[e]);
  atomicAdd(&cnt[d], 1);
}

// ---------------- Kernel 3: single-block exclusive scan over 2000 PADDED counts ----------------
__global__ __launch_bounds__(256) void k_scan(const int* __restrict__ cnt, int* __restrict__ offs)
{
  __shared__ int wsum[4];
  int tid = threadIdx.x;
  int vals[8];
  int run = 0;
  #pragma unroll
  for (int i = 0; i < 8; ++i) {
    int idx = tid * 8 + i;
    vals[i] = run;
    int v = (idx < B_N) ? cnt[idx] : 0;
    v = (v + 3) & ~3;                       // pad to multiple of 4
    run += v;
  }
  int lane = tid & 63, wid = tid >> 6;
  int xs = run;
  #pragma unroll
  for (int d = 1; d < 64; d <<= 1) {
    int y = __shfl_up(xs, d);
    if (lane >= d) xs += y;
  }
  if (lane == 63) wsum[wid] = xs;
  __syncthreads();
  int pre = 0;
  for (int w = 0; w < wid; ++w) pre += wsum[w];
  int excl = pre + xs - run;
  #pragma unroll
  for (int i = 0; i < 8; ++i) {
    int idx = tid * 8 + i;
    if (idx <= B_N) offs[idx] = excl + vals[i];
  }
}

// ---------------- Kernel 4: CSR scatter + edge norm (pad slots stay {src=0, norm=0}) ----------------
__global__ void k_scatter(const int* __restrict__ ei, const float* __restrict__ ew,
                          const float* __restrict__ deg, const int* __restrict__ offs,
                          int* __restrict__ cursor, int* __restrict__ csr_src,
                          float* __restrict__ csr_norm)
{
  int e = blockIdx.x * 256 + threadIdx.x;
  if (e >= E_N) return;
  int s = ei[e], d = ei[E_N + e];
  float ds_ = deg[s], dd = deg[d];
  float dis_s = (ds_ > 0.f) ? rsqrtf(fmaxf(ds_, 1e-12f)) : 0.f;
  float dis_d = (dd  > 0.f) ? rsqrtf(fmaxf(dd,  1e-12f)) : 0.f;
  float nrm = dis_s * ew[e] * dis_d;
  int pos = offs[d] + atomicAdd(&cursor[d], 1);
  csr_src[pos] = s;
  csr_norm[pos] = nrm;
}

// ---------------- Kernel 5: one-hop propagation, 4-wide edge unroll ----------------
__global__ __launch_bounds__(256) void k_prop(
    unsigned short* xcat, int cin, int cout_,
    const int* __restrict__ offs, const int* __restrict__ csr_src,
    const float* __restrict__ csr_norm)
{
  int gw = (blockIdx.x * 256 + threadIdx.x) >> 6;
  int lane = threadIdx.x & 63;
  if (gw >= NNODE) return;
  int t = gw / B_N;
  int b = gw - t * B_N;
  int beg = offs[b], end = offs[b + 1];           // both multiples of 4
  const unsigned short* base = xcat + (size_t)t * B_N * 384 + cin + lane * 2;
  float ax0 = 0.f, ay0 = 0.f, ax1 = 0.f, ay1 = 0.f;
  float ax2 = 0.f, ay2 = 0.f, ax3 = 0.f, ay3 = 0.f;
  for (int i = beg; i < end; i += 4) {
    int4   s4 = *(const int4*)&csr_src[i];
    float4 n4 = *(const float4*)&csr_norm[i];
    ushort2 v0 = *(const ushort2*)(base + (size_t)s4.x * 384);
    ushort2 v1 = *(const ushort2*)(base + (size_t)s4.y * 384);
    ushort2 v2 = *(const ushort2*)(base + (size_t)s4.z * 384);
    ushort2 v3 = *(const ushort2*)(base + (size_t)s4.w * 384);
    ax0 += n4.x * bf2f(v0.x); ay0 += n4.x * bf2f(v0.y);
    ax1 += n4.y * bf2f(v1.x); ay1 += n4.y * bf2f(v1.y);
    ax2 += n4.z * bf2f(v2.x); ay2 += n4.z * bf2f(v2.y);
    ax3 += n4.w * bf2f(v3.x); ay3 += n4.w * bf2f(v3.y);
  }
  float ax = (ax0 + ax1) + (ax2 + ax3);
  float ay = (ay0 + ay1) + (ay2 + ay3);
  ushort2 o; o.x = f2bf(ax); o.y = f2bf(ay);
  *(ushort2*)&xcat[(size_t)gw * 384 + cout_ + lane * 2] = o;
}

// ---------------- Kernel 6: MFMA triple-GEMM (K=384), B half in LDS fragment-order ----------------
// Block = 8 waves x 16 rows = 128 rows x 64 cols (half). Grid 1000 (500 rowblks x 2 halves).
__global__ __launch_bounds__(512, 4) void k_gemm(
    const unsigned short* __restrict__ xcat, const unsigned short* __restrict__ wB,
    const float* __restrict__ tb, float* __restrict__ outn)
{
  __shared__ unsigned short sB[24576];   // 48KB = 64 cols x 384 K, fragment-ordered
  const int bid = blockIdx.x;
  const int half = bid / 500, rowblk = bid % 500;
  const int tid = threadIdx.x;
  const int w = tid >> 6, lane = tid & 63;
  const int m0 = rowblk * 128 + w * 16;
  const int r = lane & 15, q = lane >> 4;

  // all 12 A fragments up-front (independent loads, one round trip)
  const bf16x8* arow = (const bf16x8*)(xcat + (size_t)(m0 + r) * 384 + q * 8);
  bf16x8 a[12];
  #pragma unroll
  for (int ks = 0; ks < 12; ++ks) a[ks] = arow[ks * 4];

  // linear stage of this half's fragment-ordered B (24576 elems = 3072 float4)
  const float4* gB = (const float4*)(wB + (size_t)half * 24576);
  #pragma unroll
  for (int i = 0; i < 6; ++i) {
    int id = i * 512 + tid;
    ((float4*)sB)[id] = gB[id];
  }
  __syncthreads();

  f32x4 acc[4] = {};
  #pragma unroll
  for (int ks = 0; ks < 12; ++ks) {
    #pragma unroll
    for (int nf = 0; nf < 4; ++nf) {
      bf16x8 bv = *(const bf16x8*)&sB[((nf * 12 + ks) * 64 + lane) * 8];
      acc[nf] = __builtin_amdgcn_mfma_f32_16x16x32_bf16(a[ks], bv, acc[nf], 0, 0, 0);
    }
  }

  #pragma unroll
  for (int nf = 0; nf < 4; ++nf) {
    const int col = (half * 4 + nf) * 16 + r;
    const float bias = tb[col];
    #pragma unroll
    for (int i = 0; i < 4; ++i) {
      const int row = m0 + q * 4 + i;
      float u = acc[nf][i] + bias;
      u = (u >= 0.f) ? u : NEG_S * u;
      float xv = bf2f(xcat[(size_t)row * 384 + col]);
      outn[(size_t)row * 128 + col] = xv + u;
    }
  }
}

// ---------------- Kernel 7: transpose [t*B+b][c] -> [b][c][t] ----------------
__global__ __launch_bounds__(256) void k_out(const float* __restrict__ hfin, float* __restrict__ out)
{
  __shared__ float lds[32 * 129];
  const int b = blockIdx.x, tid = threadIdx.x;
  #pragma unroll
  for (int i = 0; i < 16; ++i) {
    int idx = i * 256 + tid;
    int t = idx >> 7, c = idx & 127;
    lds[t * 129 + c] = hfin[(size_t)(t * B_N + b) * 128 + c];
  }
  __syncthreads();
  #pragma unroll
  for (int i = 0; i < 16; ++i) {
    int idx = i * 256 + tid;
    int c = idx >> 5, t = idx & 31;
    out[(size_t)b * 4096 + c * 32 + t] = lds[t * 129 + c];
  }
}

extern "C" void kernel_launch(void* const* d_in, const int* in_sizes, int n_in,
                              void* d_out, int out_size, void* d_ws, size_t ws_size,
                              hipStream_t stream)
{
  const float* x     = (const float*)d_in[0];
  const int*   ei    = (const int*)d_in[1];
  const float* ew    = (const float*)d_in[2];
  const float* cw    = (const float*)d_in[3];
  const float* cb    = (const float*)d_in[4];
  const float* gamma = (const float*)d_in[5];
  const float* beta  = (const float*)d_in[6];
  const float* tw    = (const float*)d_in[7];
  const float* tb    = (const float*)d_in[8];
  float* out = (float*)d_out;

  // workspace layout
  float* outn = (float*)d_ws;                                             // 64000*128 fp32
  unsigned short* A = (unsigned short*)outn;                              // 64000*96 bf16 aliased
                                                                          // (dead before k_gemm writes outn)
  unsigned short* xcat = (unsigned short*)(outn + (size_t)NNODE * 128);   // 64000*384 bf16
  float* deg = (float*)(xcat + (size_t)NNODE * 384);                      // 2000
  int*   cnt    = (int*)(deg + B_N);                                      // 2000
  int*   cursor = cnt + B_N;                                              // 2000
  int*   offs   = cursor + B_N;                                           // 2001 (+3 pad for 16B align)
  int*   csr_src = offs + (B_N + 4);                                      // EPAD_N, 16B-aligned
  float* csr_norm = (float*)(csr_src + EPAD_N);                           // EPAD_N
  unsigned short* wBc = (unsigned short*)(csr_norm + EPAD_N);             // 12288 bf16 frag-order
  unsigned short* wB  = wBc + 12288;                                      // 49152 bf16 frag-order

  // zero deg..csr_norm (contiguous 84036 ints) with a custom kernel:
  // rocclr's fillBufferAligned ran at ~7 GB/s (44 us in-graph) for this region.
  k_zero<<<84, 256, 0, stream>>>((int4*)deg);

  k_cwcast<<<48, 256, 0, stream>>>(cw, wBc);
  k_twt<<<192, 256, 0, stream>>>(tw, wB);
  k_im2col<<<B_N, 256, 0, stream>>>(x, A);
  k_convmm<<<500, 512, 0, stream>>>(A, wBc, cb, xcat);
  k_ln<<<B_N, 256, 0, stream>>>(xcat, gamma, beta);
  k_deg<<<(E_N + 255) / 256, 256, 0, stream>>>(ei, ew, deg, cnt);
  k_scan<<<1, 256, 0, stream>>>(cnt, offs);
  k_scatter<<<(E_N + 255) / 256, 256, 0, stream>>>(ei, ew, deg, offs, cursor, csr_src, csr_norm);
  k_prop<<<NNODE / 4, 256, 0, stream>>>(xcat, 0, 128, offs, csr_src, csr_norm);
  k_prop<<<NNODE / 4, 256, 0, stream>>>(xcat, 128, 256, offs, csr_src, csr_norm);
  k_gemm<<<1000, 512, 0, stream>>>(xcat, wB, tb, outn);
  k_out<<<B_N, 256, 0, stream>>>(outn, out);
}

// Round 9
// 155.052 us; speedup vs baseline: 1.5013x; 1.2219x over previous
//
#include <hip/hip_runtime.h>
#include <hip/hip_bf16.h>
#include <math.h>

#define B_N   2000
#define T_N   32
#define CIN_N 32
#define COUT_N 128
#define E_N   32000
#define NEG_S 0.01f
#define EPS_S 1e-5f
#define NNODE (B_N * T_N)   // 64000
#define EPAD_N 38016        // padded CSR capacity (multiple-of-4 per node)
// contiguous meta region: deg(2000)+cnt(2000)+cursor(2000)+offs(2004)+csr_src(38016)+csr_norm(38016)
#define META_I4 21009       // 84036 ints = 21009 int4

typedef __attribute__((ext_vector_type(8))) __bf16 bf16x8;
typedef __attribute__((ext_vector_type(4))) float f32x4;
typedef __attribute__((ext_vector_type(8))) unsigned short u16x8;

__device__ __forceinline__ unsigned short f2bf(float f) {
  unsigned u = __builtin_bit_cast(unsigned, f);
  u += 0x7FFFu + ((u >> 16) & 1u);   // RNE (finite values)
  return (unsigned short)(u >> 16);
}
__device__ __forceinline__ float bf2f(unsigned short h) {
  unsigned u = ((unsigned)h) << 16;
  return __builtin_bit_cast(float, u);
}

// ---------------- Kernel P: fused prep — zero meta + cast both weight tensors ----------------
// wBc[((nf2*3+ks)*64+lane)*8+e]  = cw[col*96+k],            col=nf2*16+(lane&15), k=ks*32+(lane>>4)*8+e
// wB [((nf2*12+ks)*64+lane)*8+e] = tag_w[k>>7][k&127][col], same lane mapping, K=384
__global__ __launch_bounds__(256) void k_prep(
    const float* __restrict__ cw, const float* __restrict__ tw,
    unsigned short* __restrict__ wBc, unsigned short* __restrict__ wB,
    int4* __restrict__ meta)
{
  const int tid0 = blockIdx.x * 256 + threadIdx.x;
  const int stride = gridDim.x * 256;
  const int4 z = {0, 0, 0, 0};
  for (int i = tid0; i < META_I4; i += stride) meta[i] = z;
  for (int idx = tid0; idx < 12288; idx += stride) {
    int e = idx & 7, lane = (idx >> 3) & 63, rest = idx >> 9;
    int ks = rest % 3, nf2 = rest / 3;
    int col = nf2 * 16 + (lane & 15);
    int k = ks * 32 + ((lane >> 4) << 3) + e;
    wBc[idx] = f2bf(cw[col * 96 + k]);
  }
  for (int idx = tid0; idx < 49152; idx += stride) {
    int e = idx & 7, lane = (idx >> 3) & 63, rest = idx >> 9;
    int ks = rest % 12, nf2 = rest / 12;
    int col = nf2 * 16 + (lane & 15);
    int k = ks * 32 + ((lane >> 4) << 3) + e;
    wB[idx] = f2bf(tw[(k >> 7) * 16384 + (k & 127) * 128 + col]);
  }
}

// ---------------- Kernel 1a: im2col A[t*B+b][k] bf16, k = ci*3+kk, causal pad ----------------
__global__ __launch_bounds__(256) void k_im2col(const float* __restrict__ x,
                                                unsigned short* __restrict__ A)
{
  __shared__ float sx[32 * 34];   // x[b] padded: sx[ci*34 + t+2] = x[b,ci,t]
  const int b = blockIdx.x;
  const int tid = threadIdx.x;
  for (int idx = tid; idx < 1088; idx += 256) {
    int ci = idx / 34, tt = idx - ci * 34;
    sx[idx] = (tt >= 2) ? x[b * 1024 + ci * 32 + (tt - 2)] : 0.f;
  }
  __syncthreads();
  #pragma unroll
  for (int i = 0; i < 12; ++i) {
    int idx = i * 256 + tid;                 // 3072 = 32*96
    int t = idx / 96, k = idx - t * 96;
    int ci = k / 3, kk = k - ci * 3;
    A[(size_t)(t * B_N + b) * 96 + k] = f2bf(sx[ci * 34 + t + kk]);
  }
}

// ---------------- Kernel 1b: MFMA conv GEMM, B staged in LDS fragment-order ----------------
__global__ __launch_bounds__(512, 4) void k_convmm(
    const unsigned short* __restrict__ A, const unsigned short* __restrict__ wBc,
    const float* __restrict__ cb, unsigned short* __restrict__ xcat)
{
  __shared__ unsigned short sB[12288];   // 24KB
  const int tid = threadIdx.x;
  const int w = tid >> 6, lane = tid & 63;
  const int m0 = blockIdx.x * 128 + w * 16;
  const int r = lane & 15, q = lane >> 4;

  const bf16x8* arow = (const bf16x8*)(A + (size_t)(m0 + r) * 96 + q * 8);
  bf16x8 a0 = arow[0], a1 = arow[4], a2 = arow[8];

  #pragma unroll
  for (int i = 0; i < 3; ++i) {
    int id = i * 512 + tid;
    ((float4*)sB)[id] = ((const float4*)wBc)[id];
  }
  __syncthreads();

  f32x4 acc[8] = {};
  #pragma unroll
  for (int ks = 0; ks < 3; ++ks) {
    bf16x8 a = (ks == 0) ? a0 : (ks == 1) ? a1 : a2;
    #pragma unroll
    for (int nf = 0; nf < 8; ++nf) {
      bf16x8 bv = *(const bf16x8*)&sB[((nf * 3 + ks) * 64 + lane) * 8];
      acc[nf] = __builtin_amdgcn_mfma_f32_16x16x32_bf16(a, bv, acc[nf], 0, 0, 0);
    }
  }

  #pragma unroll
  for (int nf = 0; nf < 8; ++nf) {
    const int col = nf * 16 + r;
    const float bias = cb[col];
    #pragma unroll
    for (int i = 0; i < 4; ++i) {
      const int row = m0 + q * 4 + i;
      float u = acc[nf][i] + bias;
      u = (u >= 0.f) ? u : NEG_S * u;
      xcat[(size_t)row * 384 + col] = f2bf(u);
    }
  }
}

// ---------------- Kernel 1c: per-sample LayerNorm in place, ushort8 vector I/O ----------------
__global__ __launch_bounds__(256) void k_ln(
    unsigned short* xcat, const float* __restrict__ gamma, const float* __restrict__ beta)
{
  __shared__ float red1[4], red2[4], sstat[2];
  const int b = blockIdx.x;
  const int tid = threadIdx.x;
  const int t = tid >> 4;              // 0..15 (and t+16)
  const int c0 = (tid & 15) * 8;
  const size_t i0 = (size_t)(t * B_N + b) * 384 + c0;
  const size_t i1 = (size_t)((t + 16) * B_N + b) * 384 + c0;
  u16x8 r0 = *(const u16x8*)&xcat[i0];
  u16x8 r1 = *(const u16x8*)&xcat[i1];
  float v[16];
  float s1 = 0.f, s2 = 0.f;
  #pragma unroll
  for (int j = 0; j < 8; ++j) {
    v[j] = bf2f(r0[j]); v[8 + j] = bf2f(r1[j]);
    s1 += v[j] + v[8 + j];
    s2 += v[j] * v[j] + v[8 + j] * v[8 + j];
  }
  const int lane = tid & 63, wid = tid >> 6;
  #pragma unroll
  for (int d = 32; d > 0; d >>= 1) {
    s1 += __shfl_down(s1, d);
    s2 += __shfl_down(s2, d);
  }
  if (lane == 0) { red1[wid] = s1; red2[wid] = s2; }
  __syncthreads();
  if (tid == 0) {
    float a = red1[0] + red1[1] + red1[2] + red1[3];
    float c = red2[0] + red2[1] + red2[2] + red2[3];
    float mu = a / 4096.f;
    float var = c / 4096.f - mu * mu;
    sstat[0] = mu;
    sstat[1] = rsqrtf(var + EPS_S);
  }
  __syncthreads();
  const float mu = sstat[0], rs = sstat[1];
  u16x8 o0, o1;
  #pragma unroll
  for (int j = 0; j < 8; ++j) {
    o0[j] = f2bf((v[j]     - mu) * rs * gamma[(c0 + j) * 32 + t]      + beta[(c0 + j) * 32 + t]);
    o1[j] = f2bf((v[8 + j] - mu) * rs * gamma[(c0 + j) * 32 + t + 16] + beta[(c0 + j) * 32 + t + 16]);
  }
  *(u16x8*)&xcat[i0] = o0;
  *(u16x8*)&xcat[i1] = o1;
}

// ---------------- Kernel 2: in-degree (weighted) + in-edge counts ----------------
__global__ void k_deg(const int* __restrict__ ei, const float* __restrict__ ew,
                      float* __restrict__ deg, int* __restrict__ cnt)
{
  int e = blockIdx.x * 256 + threadIdx.x;
  if (e >= E_N) return;
  int d = ei[E_N + e];
  atomicAdd(&deg[d], ew[e]);
  atomicAdd(&cnt[d], 1);
}

// ---------------- Kernel 3: single-block exclusive scan over 2000 PADDED counts ----------------
__global__ __launch_bounds__(256) void k_scan(const int* __restrict__ cnt, int* __restrict__ offs)
{
  __shared__ int wsum[4];
  int tid = threadIdx.x;
  int vals[8];
  int run = 0;
  #pragma unroll
  for (int i = 0; i < 8; ++i) {
    int idx = tid * 8 + i;
    vals[i] = run;
    int v = (idx < B_N) ? cnt[idx] : 0;
    v = (v + 3) & ~3;                       // pad to multiple of 4
    run += v;
  }
  int lane = tid & 63, wid = tid >> 6;
  int xs = run;
  #pragma unroll
  for (int d = 1; d < 64; d <<= 1) {
    int y = __shfl_up(xs, d);
    if (lane >= d) xs += y;
  }
  if (lane == 63) wsum[wid] = xs;
  __syncthreads();
  int pre = 0;
  for (int w = 0; w < wid; ++w) pre += wsum[w];
  int excl = pre + xs - run;
  #pragma unroll
  for (int i = 0; i < 8; ++i) {
    int idx = tid * 8 + i;
    if (idx <= B_N) offs[idx] = excl + vals[i];
  }
}

// ---------------- Kernel 4: CSR scatter + edge norm (pad slots stay {src=0, norm=0}) ----------------
__global__ void k_scatter(const int* __restrict__ ei, const float* __restrict__ ew,
                          const float* __restrict__ deg, const int* __restrict__ offs,
                          int* __restrict__ cursor, int* __restrict__ csr_src,
                          float* __restrict__ csr_norm)
{
  int e = blockIdx.x * 256 + threadIdx.x;
  if (e >= E_N) return;
  int s = ei[e], d = ei[E_N + e];
  float ds_ = deg[s], dd = deg[d];
  float dis_s = (ds_ > 0.f) ? rsqrtf(fmaxf(ds_, 1e-12f)) : 0.f;
  float dis_d = (dd  > 0.f) ? rsqrtf(fmaxf(dd,  1e-12f)) : 0.f;
  float nrm = dis_s * ew[e] * dis_d;
  int pos = offs[d] + atomicAdd(&cursor[d], 1);
  csr_src[pos] = s;
  csr_norm[pos] = nrm;
}

// ---------------- Kernel 5: one-hop propagation, t-paired (t and t+16) + 4-wide unroll ----------
// 1 wave per (b, tpair). 32000 waves. Reads cols [cin,cin+128), writes [cout_,cout_+128).
__global__ __launch_bounds__(256) void k_prop(
    unsigned short* xcat, int cin, int cout_,
    const int* __restrict__ offs, const int* __restrict__ csr_src,
    const float* __restrict__ csr_norm)
{
  int gw = (blockIdx.x * 256 + threadIdx.x) >> 6;
  int lane = threadIdx.x & 63;
  if (gw >= B_N * 16) return;
  int tp = gw / B_N;                 // 0..15
  int b  = gw - tp * B_N;
  int beg = offs[b], end = offs[b + 1];           // both multiples of 4
  const unsigned short* base0 = xcat + (size_t)tp * B_N * 384 + cin + lane * 2;
  const unsigned short* base1 = base0 + (size_t)16 * B_N * 384;
  float ax0 = 0.f, ay0 = 0.f, ax1 = 0.f, ay1 = 0.f;
  float ax2 = 0.f, ay2 = 0.f, ax3 = 0.f, ay3 = 0.f;
  float bx0 = 0.f, by0 = 0.f, bx1 = 0.f, by1 = 0.f;
  float bx2 = 0.f, by2 = 0.f, bx3 = 0.f, by3 = 0.f;
  for (int i = beg; i < end; i += 4) {
    int4   s4 = *(const int4*)&csr_src[i];
    float4 n4 = *(const float4*)&csr_norm[i];
    size_t o0 = (size_t)s4.x * 384, o1 = (size_t)s4.y * 384;
    size_t o2 = (size_t)s4.z * 384, o3 = (size_t)s4.w * 384;
    ushort2 v0 = *(const ushort2*)(base0 + o0);
    ushort2 v1 = *(const ushort2*)(base0 + o1);
    ushort2 v2 = *(const ushort2*)(base0 + o2);
    ushort2 v3 = *(const ushort2*)(base0 + o3);
    ushort2 u0 = *(const ushort2*)(base1 + o0);
    ushort2 u1 = *(const ushort2*)(base1 + o1);
    ushort2 u2 = *(const ushort2*)(base1 + o2);
    ushort2 u3 = *(const ushort2*)(base1 + o3);
    ax0 += n4.x * bf2f(v0.x); ay0 += n4.x * bf2f(v0.y);
    ax1 += n4.y * bf2f(v1.x); ay1 += n4.y * bf2f(v1.y);
    ax2 += n4.z * bf2f(v2.x); ay2 += n4.z * bf2f(v2.y);
    ax3 += n4.w * bf2f(v3.x); ay3 += n4.w * bf2f(v3.y);
    bx0 += n4.x * bf2f(u0.x); by0 += n4.x * bf2f(u0.y);
    bx1 += n4.y * bf2f(u1.x); by1 += n4.y * bf2f(u1.y);
    bx2 += n4.z * bf2f(u2.x); by2 += n4.z * bf2f(u2.y);
    bx3 += n4.w * bf2f(u3.x); by3 += n4.w * bf2f(u3.y);
  }
  float ax = (ax0 + ax1) + (ax2 + ax3);
  float ay = (ay0 + ay1) + (ay2 + ay3);
  float bx = (bx0 + bx1) + (bx2 + bx3);
  float by = (by0 + by1) + (by2 + by3);
  ushort2 oa; oa.x = f2bf(ax); oa.y = f2bf(ay);
  ushort2 ob; ob.x = f2bf(bx); ob.y = f2bf(by);
  *(ushort2*)&xcat[(size_t)(tp * B_N + b) * 384 + cout_ + lane * 2] = oa;
  *(ushort2*)&xcat[(size_t)((tp + 16) * B_N + b) * 384 + cout_ + lane * 2] = ob;
}

// ---------------- Kernel 6: MFMA triple-GEMM (K=384) + epilogue, direct [b][c][t] store ---------
// Wave M-tile = 16 timesteps of ONE sample b (thalf selects t0=0/16); cols 64 per chalf.
// Block = 8 waves = 8 consecutive b. Grid 1000 = 250 b-oct x {thalf,chalf}.
__global__ __launch_bounds__(512, 4) void k_gemm(
    const unsigned short* __restrict__ xcat, const unsigned short* __restrict__ wB,
    const float* __restrict__ tb, float* __restrict__ out)
{
  __shared__ unsigned short sB[24576];   // 48KB: 64 cols x 384 K, fragment-ordered
  const int tid = threadIdx.x;
  const int w = tid >> 6, lane = tid & 63;
  const int sel = blockIdx.x / 250;                  // 0..3
  const int b = (blockIdx.x % 250) * 8 + w;
  const int thalf = sel & 1, chalf = sel >> 1;
  const int t0 = thalf * 16;
  const int r = lane & 15, q = lane >> 4;

  // 12 A-fragments up-front; A-row r = timestep t0+r of sample b (per-lane 16B gathers)
  const bf16x8* arow = (const bf16x8*)(xcat + (size_t)((t0 + r) * B_N + b) * 384 + q * 8);
  bf16x8 a[12];
  #pragma unroll
  for (int ks = 0; ks < 12; ++ks) a[ks] = arow[ks * 4];

  const float4* gB = (const float4*)(wB + (size_t)chalf * 24576);
  #pragma unroll
  for (int i = 0; i < 6; ++i) {
    int id = i * 512 + tid;
    ((float4*)sB)[id] = gB[id];
  }
  __syncthreads();

  f32x4 acc[4] = {};
  #pragma unroll
  for (int ks = 0; ks < 12; ++ks) {
    #pragma unroll
    for (int nf = 0; nf < 4; ++nf) {
      bf16x8 bv = *(const bf16x8*)&sB[((nf * 12 + ks) * 64 + lane) * 8];
      acc[nf] = __builtin_amdgcn_mfma_f32_16x16x32_bf16(a[ks], bv, acc[nf], 0, 0, 0);
    }
  }

  #pragma unroll
  for (int nf = 0; nf < 4; ++nf) {
    const int col = chalf * 64 + nf * 16 + r;
    const float bias = tb[col];
    float4 o;
    #pragma unroll
    for (int i = 0; i < 4; ++i) {
      const int t = t0 + q * 4 + i;
      float u = acc[nf][i] + bias;
      u = (u >= 0.f) ? u : NEG_S * u;
      float xv = bf2f(xcat[(size_t)(t * B_N + b) * 384 + col]);   // residual = xp
      ((float*)&o)[i] = xv + u;
    }
    *(float4*)&out[(size_t)b * 4096 + col * 32 + t0 + q * 4] = o;
  }
}

extern "C" void kernel_launch(void* const* d_in, const int* in_sizes, int n_in,
                              void* d_out, int out_size, void* d_ws, size_t ws_size,
                              hipStream_t stream)
{
  const float* x     = (const float*)d_in[0];
  const int*   ei    = (const int*)d_in[1];
  const float* ew    = (const float*)d_in[2];
  const float* cw    = (const float*)d_in[3];
  const float* cb    = (const float*)d_in[4];
  const float* gamma = (const float*)d_in[5];
  const float* beta  = (const float*)d_in[6];
  const float* tw    = (const float*)d_in[7];
  const float* tb    = (const float*)d_in[8];
  float* out = (float*)d_out;

  // workspace layout (no fp32 outn anymore; k_gemm writes d_out directly)
  unsigned short* A    = (unsigned short*)d_ws;                 // 64000*96 bf16
  unsigned short* xcat = A + (size_t)NNODE * 96;                // 64000*384 bf16
  float* deg = (float*)(xcat + (size_t)NNODE * 384);            // 2000 (16B aligned)
  int*   cnt    = (int*)(deg + B_N);                            // 2000
  int*   cursor = cnt + B_N;                                    // 2000
  int*   offs   = cursor + B_N;                                 // 2004 (padded for 16B align)
  int*   csr_src = offs + (B_N + 4);                            // EPAD_N
  float* csr_norm = (float*)(csr_src + EPAD_N);                 // EPAD_N
  unsigned short* wBc = (unsigned short*)(csr_norm + EPAD_N);   // 12288 bf16 frag-order
  unsigned short* wB  = wBc + 12288;                            // 49152 bf16 frag-order

  k_prep<<<96, 256, 0, stream>>>(cw, tw, wBc, wB, (int4*)deg);
  k_im2col<<<B_N, 256, 0, stream>>>(x, A);
  k_convmm<<<500, 512, 0, stream>>>(A, wBc, cb, xcat);
  k_ln<<<B_N, 256, 0, stream>>>(xcat, gamma, beta);
  k_deg<<<(E_N + 255) / 256, 256, 0, stream>>>(ei, ew, deg, cnt);
  k_scan<<<1, 256, 0, stream>>>(cnt, offs);
  k_scatter<<<(E_N + 255) / 256, 256, 0, stream>>>(ei, ew, deg, offs, cursor, csr_src, csr_norm);
  k_prop<<<B_N * 16 / 4, 256, 0, stream>>>(xcat, 0, 128, offs, csr_src, csr_norm);
  k_prop<<<B_N * 16 / 4, 256, 0, stream>>>(xcat, 128, 256, offs, csr_src, csr_norm);
  k_gemm<<<1000, 512, 0, stream>>>(xcat, wB, tb, out);
}